// Round 8
// baseline (754.018 us; speedup 1.0000x reference)
//
#include <hip/hip_runtime.h>
#include <cstdint>
#include <cstddef>

#define BATCH 8
#define CIN 64
#define HIN 70
#define HOUT 64
#define NPIX 4096
#define MPIX 1024

typedef __attribute__((ext_vector_type(8))) short short8;
typedef __attribute__((ext_vector_type(4))) float f32x4;
typedef __attribute__((ext_vector_type(4))) unsigned int uint4v;

__device__ __forceinline__ unsigned short f2bf_rne(float f) {
  unsigned int u = __builtin_bit_cast(unsigned int, f);
  unsigned int r = (u + 0x7FFFu + ((u >> 16) & 1u)) >> 16;
  return (unsigned short)r;
}

__device__ __forceinline__ unsigned int rot16(unsigned int u) {
  return (u >> 16) | (u << 16);
}

// ---------------------------------------------------------------------------
// prep_x: x [8][64][70][70] f32 -> xTi [8][70][70][128] ushort (hi/lo pairs)
// ---------------------------------------------------------------------------
__global__ __launch_bounds__(256) void prep_x(const float* __restrict__ x,
                                              unsigned int* __restrict__ xTi) {
  __shared__ float tile[64][71];
  const int blk = blockIdx.x;  // 0..559
  const int b = blk / 70;
  const int r = blk - b * 70;
  const int t = threadIdx.x;
  for (int i = t; i < 64 * 70; i += 256) {
    int ci = i / 70;
    int c = i - ci * 70;
    tile[ci][c] = x[(((size_t)(b * 64 + ci)) * 70 + r) * 70 + c];
  }
  __syncthreads();
  for (int i = t; i < 70 * 64; i += 256) {
    int c = i >> 6;
    int ci = i & 63;
    float a = tile[ci][c];
    unsigned short hi = f2bf_rne(a);
    float hif = __builtin_bit_cast(float, ((unsigned int)hi) << 16);
    unsigned short lo = f2bf_rne(a - hif);
    xTi[(((size_t)(b * 70 + r)) * 70 + c) * 64 + ci] =
        (unsigned int)hi | (((unsigned int)lo) << 16);
  }
}

// ---------------------------------------------------------------------------
// prep_w: weights -> wTi [49 s][448 OC][64 dw] (hi/lo pairs).
// OC: 0..99 theta, 100..199 phi, 200..399 g, 400..447 zero-pad
// ---------------------------------------------------------------------------
__global__ __launch_bounds__(256) void prep_w(
    const float* __restrict__ tw, const float* __restrict__ pw,
    const float* __restrict__ gw, unsigned int* __restrict__ wTi) {
  int gid = blockIdx.x * 256 + threadIdx.x;  // 49*448*64 = 1,404,928 dwords
  if (gid >= 49 * 448 * 64) return;
  int ci = gid & 63;
  int OC = (gid >> 6) % 448;
  int s = gid / (448 * 64);
  float v = 0.0f;
  if (OC < 100) v = tw[((size_t)(OC * 64 + ci)) * 49 + s];
  else if (OC < 200) v = pw[((size_t)((OC - 100) * 64 + ci)) * 49 + s];
  else if (OC < 400) v = gw[((size_t)((OC - 200) * 64 + ci)) * 49 + s];
  unsigned short hi = f2bf_rne(v);
  float hif = __builtin_bit_cast(float, ((unsigned int)hi) << 16);
  unsigned short lo = f2bf_rne(v - hif);
  wTi[gid] = (unsigned int)hi | (((unsigned int)lo) << 16);
}

__global__ __launch_bounds__(256) void prep_bias(
    const float* __restrict__ tb, const float* __restrict__ pb,
    const float* __restrict__ gb, float* __restrict__ biasPad) {
  int i = blockIdx.x * 256 + threadIdx.x;
  if (i >= 448) return;
  float v = 0.0f;
  if (i < 100) v = tb[i];
  else if (i < 200) v = pb[i - 100];
  else if (i < 400) v = gb[i - 200];
  biasPad[i] = v;
}

// ---------------------------------------------------------------------------
// zero_pads: zero channel-pad regions of thd/phd (dw 100..127) and gP rows
// c=200..207 so MFMA K-padding contributes exactly 0.
// ---------------------------------------------------------------------------
__global__ __launch_bounds__(256) void zero_pads(
    unsigned int* __restrict__ thd_dw, unsigned int* __restrict__ phd_dw,
    unsigned int* __restrict__ g_dw) {
  int i = blockIdx.x * 256 + threadIdx.x;
  if (i < 917504) {
    int n = i / 28;
    int dw = 100 + (i - n * 28);
    thd_dw[((size_t)n << 7) + dw] = 0;
  } else if (i < 917504 + 229376) {
    int j = i - 917504;
    int m = j / 28;
    int dw = 100 + (j - m * 28);
    phd_dw[((size_t)m << 7) + dw] = 0;
  } else if (i < 917504 + 229376 + 32768) {
    int j = i - (917504 + 229376);
    int b = j >> 12;
    int off = j & 4095;
    g_dw[(size_t)b * 106496 + 102400 + off] = 0;
  }
}

// ---------------------------------------------------------------------------
// convmfma v4: dual-bf16 implicit-GEMM conv, 512-thread / 8-row blocks.
//  - grid (64, 7): x = b*8+ptile (8 output rows), y = 64-oc tile of 448
//  - 8 waves; wave wv = output row py = oy0+wv, owns 64 oc x 64 cols
//    acc[4 ocfrag][4 pxfrag]; 32 dual-MFMA per slice (verbatim r7 compute)
//  - X [14][70][64B] staged per 16-ci chunk (swizzled, 62720 B)
//  - W staged in TWO 8KB pair-slots (2 slices each); one barrier per PAIR
//    (100 barriers/block vs r7's 196); register prefetch 2 pairs ahead
//  - 49 slices = 24 pairs + tail (pair 24 clamped to slice 48)
//  - epilogue: theta full-res dual-bf16; phi/g 2x2 maxpool with cross-wave
//    row-pair exchange through LDS scratch (r6/r7-verified logic)
// ---------------------------------------------------------------------------
__global__ __launch_bounds__(512, 4) void convmfma_kernel(
    const unsigned short* __restrict__ xTi,  // [8][70][70][128]
    const unsigned short* __restrict__ wTi,  // [49][448][128]
    const float* __restrict__ biasPad,       // [448]
    unsigned int* __restrict__ thd_dw,       // [8][4096][128]
    unsigned int* __restrict__ phd_dw,       // [8][1024][128]
    unsigned short* __restrict__ gP) {       // [8][208][1024]
  __shared__ __align__(16) char smem[62720 + 16384];
  const int LDSW = 62720;

  const int gx = blockIdx.x;      // 0..63
  const int b = gx >> 3;
  const int ptile = gx & 7;
  const int oy0 = ptile * 8;
  const int oc0 = blockIdx.y << 6;  // 0..384

  const int t = threadIdx.x;      // 0..511
  const int wv = t >> 6;          // 0..7 : output row within block
  const int l = t & 63;
  const int lm = l & 15;
  const int lg = l >> 4;
  const int py = oy0 + wv;

  // W staging ids: sub-slice (0/1 within pair), oc row, 16B quarter
  const int sub = t >> 8;         // 0..1
  const int oc_t = (t >> 2) & 63; // 0..63
  const int q = t & 3;
  const int wdstOff =
      sub * 4096 + (oc_t << 6) + ((q << 4) ^ (((oc_t >> 1) & 3) << 4));
  const int keyA = ((lm >> 1) & 3) << 4;
  const int laneA = (lm << 6) + ((lg << 4) ^ keyA);

  f32x4 acc[4][4];  // [oc j][px f]
#pragma unroll
  for (int j = 0; j < 4; ++j)
#pragma unroll
    for (int f = 0; f < 4; ++f) acc[j][f] = (f32x4)0.0f;

  for (int chunk = 0; chunk < 4; ++chunk) {
    // (trailing barrier of previous chunk's last pair drained all reads)
    // ---- stage X chunk: [14][70] lines of 64B, 16B-quarter XOR swizzle
    for (int i = t; i < 3920; i += 512) {
      int idx70 = i >> 2;
      int s16 = i & 3;
      int rr = idx70 / 70;
      int cc = idx70 - rr * 70;
      const unsigned short* src =
          xTi + ((((size_t)(b * 70 + oy0 + rr)) * 70 + cc) << 7) +
          (chunk << 5) + (s16 << 3);
      short8 v = *(const short8*)src;
      int dst = (idx70 << 6) + ((s16 << 4) ^ (((cc >> 1) & 3) << 4));
      *(short8*)(smem + dst) = v;
    }
    // ---- W pipeline prologue: slot0 <- pair0; wreg <- pair1
    const unsigned short* wsrcBase =
        wTi + ((size_t)(oc0 + oc_t) << 7) + (chunk << 5) + (q << 3);
    short8 wreg = *(const short8*)(wsrcBase + (size_t)sub * 57344);  // pair 0
    *(short8*)(smem + LDSW + wdstOff) = wreg;                        // slot 0
    wreg = *(const short8*)(wsrcBase + (size_t)(2 + sub) * 57344);   // pair 1
    __syncthreads();  // X staged + slot0 visible

    for (int p = 0; p < 25; ++p) {
      const char* slotBase = smem + LDSW + ((p & 1) << 13);
#pragma unroll
      for (int halfs = 0; halfs < 2; ++halfs) {
        const int s = 2 * p + halfs;
        if (s <= 48) {
          const int ky = s / 7;
          const int kx = s - ky * 7;
          // ---- A frags (weights) + pair-swapped copies
          const char* wb = slotBase + (halfs << 12) + laneA;
          short8 aW[4], aS[4];
#pragma unroll
          for (int j = 0; j < 4; ++j) {
            aW[j] = *(const short8*)(wb + j * 1024);
            uint4v u = __builtin_bit_cast(uint4v, aW[j]);
            u.x = rot16(u.x); u.y = rot16(u.y);
            u.z = rot16(u.z); u.w = rot16(u.w);
            aS[j] = __builtin_bit_cast(short8, u);
          }
          // ---- B frags (X pixels) + MFMA
          const int klx = kx + lm;
          const int key = ((klx >> 1) & 3) << 4;
          const char* bbase =
              smem + ((wv + ky) * 70 + klx) * 64 + ((lg << 4) ^ key);
#pragma unroll
          for (int f = 0; f < 4; ++f) {
            short8 bf = *(const short8*)(bbase + f * 1024);
#pragma unroll
            for (int j = 0; j < 4; ++j) {
              acc[j][f] = __builtin_amdgcn_mfma_f32_16x16x32_bf16(
                  aW[j], bf, acc[j][f], 0, 0, 0);
              acc[j][f] = __builtin_amdgcn_mfma_f32_16x16x32_bf16(
                  aS[j], bf, acc[j][f], 0, 0, 0);
            }
          }
        }
      }
      // ---- W pipeline: write pair p+1 into other slot; prefetch pair p+2
      if (p < 24) {
        *(short8*)(smem + LDSW + (((p + 1) & 1) << 13) + wdstOff) = wreg;
        if (p < 23) {
          int snext = 2 * (p + 2) + sub;
          if (snext > 48) snext = 48;  // clamp (pair 24 tail)
          wreg = *(const short8*)(wsrcBase + (size_t)snext * 57344);
        }
      }
      __syncthreads();  // one barrier per PAIR of slices
    }
  }

  // ---- epilogue (r7-verified logic, 8-row geometry) ----
  float bia[4][4];
#pragma unroll
  for (int j = 0; j < 4; ++j)
#pragma unroll
    for (int r = 0; r < 4; ++r) bia[j][r] = biasPad[oc0 + j * 16 + lg * 4 + r];

  // theta full-res dual-bf16 (no smem involved)
#pragma unroll
  for (int j = 0; j < 4; ++j) {
#pragma unroll
    for (int f = 0; f < 4; ++f) {
#pragma unroll
      for (int r = 0; r < 4; ++r) {
        int ch = oc0 + j * 16 + lg * 4 + r;
        if (ch < 100) {
          int n = py * 64 + f * 16 + lm;
          float v = acc[j][f][r] + bia[j][r];
          unsigned short hi = f2bf_rne(v);
          float hif = __builtin_bit_cast(float, ((unsigned int)hi) << 16);
          unsigned short lo = f2bf_rne(v - hif);
          thd_dw[(((size_t)(b << 12) + n) << 7) + ch] =
              (unsigned int)hi | (((unsigned int)lo) << 16);
        }
      }
    }
  }

  __syncthreads();  // all waves done with smem compute reads
  float* scratch = (float*)smem;  // [4][64*33] floats (odd-row stash)

#pragma unroll
  for (int j = 0; j < 4; ++j) {
#pragma unroll
    for (int f = 0; f < 4; ++f) {
#pragma unroll
      for (int r = 0; r < 4; ++r) {
        float v = acc[j][f][r] + bia[j][r];
        float vn = fmaxf(v, __shfl_xor(v, 1));
        acc[j][f][r] = vn;  // keep for even waves
        if ((wv & 1) && !(lm & 1)) {
          int ch_local = j * 16 + lg * 4 + r;
          int mcol = f * 8 + (lm >> 1);
          scratch[(wv >> 1) * 2112 + ch_local * 33 + mcol] = vn;
        }
      }
    }
  }
  __syncthreads();

  if (!(wv & 1)) {
#pragma unroll
    for (int j = 0; j < 4; ++j) {
#pragma unroll
      for (int f = 0; f < 4; ++f) {
#pragma unroll
        for (int r = 0; r < 4; ++r) {
          if (!(lm & 1)) {
            int ch = oc0 + j * 16 + lg * 4 + r;
            int ch_local = j * 16 + lg * 4 + r;
            int mcol = f * 8 + (lm >> 1);
            float partner = scratch[(wv >> 1) * 2112 + ch_local * 33 + mcol];
            float vfinal = fmaxf(acc[j][f][r], partner);
            int m = (((oy0 >> 1) + (wv >> 1)) << 5) + mcol;
            if (ch >= 100 && ch < 200) {
              int c = ch - 100;
              unsigned short hi = f2bf_rne(vfinal);
              float hif = __builtin_bit_cast(float, ((unsigned int)hi) << 16);
              unsigned short lo = f2bf_rne(vfinal - hif);
              phd_dw[(((size_t)(b << 10) + m) << 7) + c] =
                  (unsigned int)hi | (((unsigned int)lo) << 16);
            } else if (ch >= 200 && ch < 400) {
              int cg = ch - 200;
              gP[((size_t)(b * 208 + cg) << 10) + m] = f2bf_rne(vfinal);
            }
          }
        }
      }
    }
  }
}

// ---------------------------------------------------------------------------
// attn_mfma: flash-style attention (unchanged from round 5, verified)
// ---------------------------------------------------------------------------
__global__ __launch_bounds__(512, 2) void attn_mfma_kernel(
    const unsigned short* __restrict__ thd,  // [8][4096][256]
    const unsigned short* __restrict__ phd,  // [8][1024][256]
    const unsigned short* __restrict__ gP,   // [8][208][1024]
    float* __restrict__ out) {               // [8][200][4096]
  __shared__ __align__(16) char sm[140800];
  float* corrL = (float*)(sm + 131072);   // [64][32]
  float* statsL = (float*)(sm + 139264);  // [64][2][2]
  float* mFinL = (float*)(sm + 140288);   // [64]
  float* invL = (float*)(sm + 140544);    // [64]

  const int bx = blockIdx.x;
  const int b = bx >> 6;
  const int n0 = (bx & 63) << 6;
  const int t = threadIdx.x;
  const int w = t >> 6;
  const int l = t & 63;
  const int lm = l & 15;
  const int lg = l >> 4;
  const int rowTile = w & 3;
  const int mhalf = w >> 2;
  const int rowB = rowTile * 16 + lg * 4;

  short8 aA[8], aS[8];
  {
    const unsigned short* ap =
        thd + (((size_t)(b << 12) + n0 + rowTile * 16 + lm) << 8) + lg * 8;
#pragma unroll
    for (int kf = 0; kf < 8; ++kf) {
      short8 v = *(const short8*)(ap + kf * 32);
      aA[kf] = v;
      uint4v u = __builtin_bit_cast(uint4v, v);
      u.x = rot16(u.x); u.y = rot16(u.y); u.z = rot16(u.z); u.w = rot16(u.w);
      aS[kf] = __builtin_bit_cast(short8, u);
    }
  }

  float mRun[4], sRun[4];
#pragma unroll
  for (int r = 0; r < 4; ++r) { mRun[r] = -3.0e38f; sRun[r] = 0.0f; }

  for (int step = 0; step < 16; ++step) {
    const int m0 = mhalf * 512 + step * 32;
    f32x4 ac0 = (f32x4)0.f, ac1 = (f32x4)0.f;
    const unsigned short* bp0 =
        phd + (((size_t)(b << 10) + m0 + lm) << 8) + lg * 8;
    const unsigned short* bp1 = bp0 + (16 << 8);
#pragma unroll
    for (int kf = 0; kf < 8; ++kf) {
      short8 bv0 = *(const short8*)(bp0 + kf * 32);
      short8 bv1 = *(const short8*)(bp1 + kf * 32);
      ac0 = __builtin_amdgcn_mfma_f32_16x16x32_bf16(aA[kf], bv0, ac0, 0, 0, 0);
      ac1 = __builtin_amdgcn_mfma_f32_16x16x32_bf16(aA[kf], bv1, ac1, 0, 0, 0);
      ac0 = __builtin_amdgcn_mfma_f32_16x16x32_bf16(aS[kf], bv0, ac0, 0, 0, 0);
      ac1 = __builtin_amdgcn_mfma_f32_16x16x32_bf16(aS[kf], bv1, ac1, 0, 0, 0);
    }
    float tmax[4], pv0[4], pv1[4], csum[4];
#pragma unroll
    for (int r = 0; r < 4; ++r) tmax[r] = fmaxf(ac0[r], ac1[r]);
#pragma unroll
    for (int s = 1; s < 16; s <<= 1)
#pragma unroll
      for (int r = 0; r < 4; ++r) tmax[r] = fmaxf(tmax[r], __shfl_xor(tmax[r], s));
#pragma unroll
    for (int r = 0; r < 4; ++r) {
      float mNew = fmaxf(mRun[r], tmax[r]);
      float scale = __expf(mRun[r] - mNew);
      pv0[r] = __expf(ac0[r] - mNew);
      pv1[r] = __expf(ac1[r] - mNew);
      csum[r] = pv0[r] + pv1[r];
      mRun[r] = mNew;
      sRun[r] *= scale;
    }
#pragma unroll
    for (int s = 1; s < 16; s <<= 1)
#pragma unroll
      for (int r = 0; r < 4; ++r) csum[r] += __shfl_xor(csum[r], s);
#pragma unroll
    for (int r = 0; r < 4; ++r) sRun[r] += csum[r];
#pragma unroll
    for (int r = 0; r < 4; ++r) {
      int row = rowB + r;
      int sw = ((row & 7) << 4);
      int byte0 = (row << 11) + ((((m0 + lm) << 1)) ^ sw);
      int byte1 = (row << 11) + ((((m0 + 16 + lm) << 1)) ^ sw);
      *(unsigned short*)(sm + byte0) = f2bf_rne(pv0[r]);
      *(unsigned short*)(sm + byte1) = f2bf_rne(pv1[r]);
    }
    if (lm == 0) {
      int chunkIdx = mhalf * 16 + step;
#pragma unroll
      for (int r = 0; r < 4; ++r) corrL[(rowB + r) * 32 + chunkIdx] = mRun[r];
    }
  }
  if (lm == 0) {
#pragma unroll
    for (int r = 0; r < 4; ++r) {
      statsL[((rowB + r) * 2 + mhalf) * 2 + 0] = mRun[r];
      statsL[((rowB + r) * 2 + mhalf) * 2 + 1] = sRun[r];
    }
  }
  __syncthreads();

  if (t < 64) {
    float m0v = statsL[(t * 2 + 0) * 2 + 0];
    float s0v = statsL[(t * 2 + 0) * 2 + 1];
    float m1v = statsL[(t * 2 + 1) * 2 + 0];
    float s1v = statsL[(t * 2 + 1) * 2 + 1];
    float mF = fmaxf(m0v, m1v);
    float sF = s0v * __expf(m0v - mF) + s1v * __expf(m1v - mF);
    mFinL[t] = mF;
    invL[t] = 1.0f / sF;
  }
  __syncthreads();

  {
    int idx = t * 4;
#pragma unroll
    for (int i = 0; i < 4; ++i) {
      int row = (idx + i) >> 5;
      corrL[idx + i] = __expf(corrL[idx + i] - mFinL[row]);
    }
  }
  __syncthreads();

  {
    int row = t >> 3;
    int mb = (t & 7) << 7;
    int sw = ((row & 7) << 4);
    for (int j = 0; j < 16; ++j) {
      int m = mb + j * 8;
      int byte = (row << 11) + (((m << 1)) ^ sw);
      float corr = corrL[row * 32 + (m >> 5)];
      short8 pv8 = *(short8*)(sm + byte);
      short8 ov;
#pragma unroll
      for (int e = 0; e < 8; ++e) {
        unsigned short us = (unsigned short)pv8[e];
        float f = __builtin_bit_cast(float, ((unsigned int)us) << 16);
        ov[e] = (short)f2bf_rne(f * corr);
      }
      *(short8*)(sm + byte) = ov;
    }
  }
  __syncthreads();

  const int nct = mhalf ? 6 : 7;
  const int ct0 = mhalf ? 7 : 0;
  f32x4 oacc[7];
#pragma unroll
  for (int i = 0; i < 7; ++i) oacc[i] = (f32x4)0.f;

  const int rowA = rowTile * 16 + lm;
  const int swA = ((rowA & 7) << 4);
  const int rowABase = (rowA << 11);

  for (int ks = 0; ks < 32; ++ks) {
    short8 ap = *(const short8*)(
        sm + rowABase + ((((ks * 32 + lg * 8) << 1)) ^ swA));
    const unsigned short* gbase =
        gP + ((size_t)(b * 208) << 10) + ks * 32 + lg * 8;
#pragma unroll
    for (int i = 0; i < 7; ++i) {
      if (i < nct) {
        int c = (ct0 + i) * 16 + lm;
        short8 gv = *(const short8*)(gbase + ((size_t)c << 10));
        oacc[i] = __builtin_amdgcn_mfma_f32_16x16x32_bf16(ap, gv, oacc[i], 0, 0, 0);
      }
    }
  }
  {
    float inv[4];
#pragma unroll
    for (int r = 0; r < 4; ++r) inv[r] = invL[rowB + r];
#pragma unroll
    for (int i = 0; i < 7; ++i) {
      if (i < nct) {
        int c = (ct0 + i) * 16 + lm;
        if (c < 200) {
          f32x4 v;
#pragma unroll
          for (int r = 0; r < 4; ++r) v[r] = oacc[i][r] * inv[r];
          *(f32x4*)(out + (((size_t)(b * 200 + c)) << 12) + n0 + rowB) = v;
        }
      }
    }
  }
}

// ---------------------------------------------------------------------------
extern "C" void kernel_launch(void* const* d_in, const int* in_sizes, int n_in,
                              void* d_out, int out_size, void* d_ws,
                              size_t ws_size, hipStream_t stream) {
  const float* x  = (const float*)d_in[0];
  const float* tw = (const float*)d_in[1];
  const float* tb = (const float*)d_in[2];
  const float* pw = (const float*)d_in[3];
  const float* pb = (const float*)d_in[4];
  const float* gw = (const float*)d_in[5];
  const float* gb = (const float*)d_in[6];
  float* out = (float*)d_out;

  unsigned short* ws_us = (unsigned short*)d_ws;
  unsigned short* thd = ws_us;               // 8*4096*256     = 8,388,608 us
  unsigned short* phd = ws_us + 8388608;     // 8*1024*256     = 2,097,152
  unsigned short* gP  = ws_us + 10485760;    // 8*208*1024     = 1,703,936
  unsigned short* xTi = ws_us + 12189696;    // 8*70*70*128    = 5,017,600
  unsigned short* wTi = ws_us + 17207296;    // 49*448*128     = 2,809,856
  float* biasPad = (float*)(ws_us + 20017152);  // 448 f (~40.1 MB total)

  prep_x<<<560, 256, 0, stream>>>(x, (unsigned int*)xTi);
  prep_w<<<5488, 256, 0, stream>>>(tw, pw, gw, (unsigned int*)wTi);
  prep_bias<<<2, 256, 0, stream>>>(tb, pb, gb, biasPad);
  zero_pads<<<4608, 256, 0, stream>>>((unsigned int*)thd, (unsigned int*)phd,
                                      (unsigned int*)gP);

  convmfma_kernel<<<dim3(64, 7), 512, 0, stream>>>(
      xTi, wTi, biasPad, (unsigned int*)thd, (unsigned int*)phd, gP);
  attn_mfma_kernel<<<512, 512, 0, stream>>>(thd, phd, gP, out);
}

// Round 9
// 511.574 us; speedup vs baseline: 1.4739x; 1.4739x over previous
//
#include <hip/hip_runtime.h>
#include <cstdint>
#include <cstddef>

#define BATCH 8
#define CIN 64
#define HIN 70
#define HOUT 64
#define NPIX 4096
#define MPIX 1024

typedef __attribute__((ext_vector_type(8))) short short8;
typedef __attribute__((ext_vector_type(4))) float f32x4;
typedef __attribute__((ext_vector_type(4))) unsigned int uint4v;

__device__ __forceinline__ unsigned short f2bf_rne(float f) {
  unsigned int u = __builtin_bit_cast(unsigned int, f);
  unsigned int r = (u + 0x7FFFu + ((u >> 16) & 1u)) >> 16;
  return (unsigned short)r;
}

__device__ __forceinline__ unsigned int rot16(unsigned int u) {
  return (u >> 16) | (u << 16);
}

// ---------------------------------------------------------------------------
// prep_x: x [8][64][70][70] f32 -> xTi [8][70][70][128] ushort (hi/lo pairs)
// ---------------------------------------------------------------------------
__global__ __launch_bounds__(256) void prep_x(const float* __restrict__ x,
                                              unsigned int* __restrict__ xTi) {
  __shared__ float tile[64][71];
  const int blk = blockIdx.x;  // 0..559
  const int b = blk / 70;
  const int r = blk - b * 70;
  const int t = threadIdx.x;
  for (int i = t; i < 64 * 70; i += 256) {
    int ci = i / 70;
    int c = i - ci * 70;
    tile[ci][c] = x[(((size_t)(b * 64 + ci)) * 70 + r) * 70 + c];
  }
  __syncthreads();
  for (int i = t; i < 70 * 64; i += 256) {
    int c = i >> 6;
    int ci = i & 63;
    float a = tile[ci][c];
    unsigned short hi = f2bf_rne(a);
    float hif = __builtin_bit_cast(float, ((unsigned int)hi) << 16);
    unsigned short lo = f2bf_rne(a - hif);
    xTi[(((size_t)(b * 70 + r)) * 70 + c) * 64 + ci] =
        (unsigned int)hi | (((unsigned int)lo) << 16);
  }
}

// ---------------------------------------------------------------------------
// prep_w: weights -> wTi [49 s][448 OC][64 dw] (hi/lo pairs).
// OC: 0..99 theta, 100..199 phi, 200..399 g, 400..447 zero-pad
// ---------------------------------------------------------------------------
__global__ __launch_bounds__(256) void prep_w(
    const float* __restrict__ tw, const float* __restrict__ pw,
    const float* __restrict__ gw, unsigned int* __restrict__ wTi) {
  int gid = blockIdx.x * 256 + threadIdx.x;  // 49*448*64 = 1,404,928 dwords
  if (gid >= 49 * 448 * 64) return;
  int ci = gid & 63;
  int OC = (gid >> 6) % 448;
  int s = gid / (448 * 64);
  float v = 0.0f;
  if (OC < 100) v = tw[((size_t)(OC * 64 + ci)) * 49 + s];
  else if (OC < 200) v = pw[((size_t)((OC - 100) * 64 + ci)) * 49 + s];
  else if (OC < 400) v = gw[((size_t)((OC - 200) * 64 + ci)) * 49 + s];
  unsigned short hi = f2bf_rne(v);
  float hif = __builtin_bit_cast(float, ((unsigned int)hi) << 16);
  unsigned short lo = f2bf_rne(v - hif);
  wTi[gid] = (unsigned int)hi | (((unsigned int)lo) << 16);
}

__global__ __launch_bounds__(256) void prep_bias(
    const float* __restrict__ tb, const float* __restrict__ pb,
    const float* __restrict__ gb, float* __restrict__ biasPad) {
  int i = blockIdx.x * 256 + threadIdx.x;
  if (i >= 448) return;
  float v = 0.0f;
  if (i < 100) v = tb[i];
  else if (i < 200) v = pb[i - 100];
  else if (i < 400) v = gb[i - 200];
  biasPad[i] = v;
}

// ---------------------------------------------------------------------------
// zero_pads: zero channel-pad regions of thd/phd (dw 100..127) and gP rows
// c=200..207 so MFMA K-padding contributes exactly 0.
// ---------------------------------------------------------------------------
__global__ __launch_bounds__(256) void zero_pads(
    unsigned int* __restrict__ thd_dw, unsigned int* __restrict__ phd_dw,
    unsigned int* __restrict__ g_dw) {
  int i = blockIdx.x * 256 + threadIdx.x;
  if (i < 917504) {
    int n = i / 28;
    int dw = 100 + (i - n * 28);
    thd_dw[((size_t)n << 7) + dw] = 0;
  } else if (i < 917504 + 229376) {
    int j = i - 917504;
    int m = j / 28;
    int dw = 100 + (j - m * 28);
    phd_dw[((size_t)m << 7) + dw] = 0;
  } else if (i < 917504 + 229376 + 32768) {
    int j = i - (917504 + 229376);
    int b = j >> 12;
    int off = j & 4095;
    g_dw[(size_t)b * 106496 + 102400 + off] = 0;
  }
}

// ---------------------------------------------------------------------------
// convmfma v4b: dual-bf16 implicit-GEMM conv, 512-thread / 8-row blocks.
// IDENTICAL to round-8 structure; launch_bounds fixed (512,2) so the
// accumulators stay in VGPRs (r8's (512,4) capped VGPR=64 -> scratch spill,
// 1 GB of write traffic). Occupancy 2 blocks/CU comes from 79KB LDS.
// ---------------------------------------------------------------------------
__global__ __launch_bounds__(512, 2) void convmfma_kernel(
    const unsigned short* __restrict__ xTi,  // [8][70][70][128]
    const unsigned short* __restrict__ wTi,  // [49][448][128]
    const float* __restrict__ biasPad,       // [448]
    unsigned int* __restrict__ thd_dw,       // [8][4096][128]
    unsigned int* __restrict__ phd_dw,       // [8][1024][128]
    unsigned short* __restrict__ gP) {       // [8][208][1024]
  __shared__ __align__(16) char smem[62720 + 16384];
  const int LDSW = 62720;

  const int gx = blockIdx.x;      // 0..63
  const int b = gx >> 3;
  const int ptile = gx & 7;
  const int oy0 = ptile * 8;
  const int oc0 = blockIdx.y << 6;  // 0..384

  const int t = threadIdx.x;      // 0..511
  const int wv = t >> 6;          // 0..7 : output row within block
  const int l = t & 63;
  const int lm = l & 15;
  const int lg = l >> 4;
  const int py = oy0 + wv;

  // W staging ids: sub-slice (0/1 within pair), oc row, 16B quarter
  const int sub = t >> 8;         // 0..1
  const int oc_t = (t >> 2) & 63; // 0..63
  const int q = t & 3;
  const int wdstOff =
      sub * 4096 + (oc_t << 6) + ((q << 4) ^ (((oc_t >> 1) & 3) << 4));
  const int keyA = ((lm >> 1) & 3) << 4;
  const int laneA = (lm << 6) + ((lg << 4) ^ keyA);

  f32x4 acc[4][4];  // [oc j][px f]
#pragma unroll
  for (int j = 0; j < 4; ++j)
#pragma unroll
    for (int f = 0; f < 4; ++f) acc[j][f] = (f32x4)0.0f;

  for (int chunk = 0; chunk < 4; ++chunk) {
    // (trailing barrier of previous chunk's last pair drained all reads)
    // ---- stage X chunk: [14][70] lines of 64B, 16B-quarter XOR swizzle
    for (int i = t; i < 3920; i += 512) {
      int idx70 = i >> 2;
      int s16 = i & 3;
      int rr = idx70 / 70;
      int cc = idx70 - rr * 70;
      const unsigned short* src =
          xTi + ((((size_t)(b * 70 + oy0 + rr)) * 70 + cc) << 7) +
          (chunk << 5) + (s16 << 3);
      short8 v = *(const short8*)src;
      int dst = (idx70 << 6) + ((s16 << 4) ^ (((cc >> 1) & 3) << 4));
      *(short8*)(smem + dst) = v;
    }
    // ---- W pipeline prologue: slot0 <- pair0; wreg <- pair1
    const unsigned short* wsrcBase =
        wTi + ((size_t)(oc0 + oc_t) << 7) + (chunk << 5) + (q << 3);
    short8 wreg = *(const short8*)(wsrcBase + (size_t)sub * 57344);  // pair 0
    *(short8*)(smem + LDSW + wdstOff) = wreg;                        // slot 0
    wreg = *(const short8*)(wsrcBase + (size_t)(2 + sub) * 57344);   // pair 1
    __syncthreads();  // X staged + slot0 visible

    for (int p = 0; p < 25; ++p) {
      const char* slotBase = smem + LDSW + ((p & 1) << 13);
#pragma unroll
      for (int halfs = 0; halfs < 2; ++halfs) {
        const int s = 2 * p + halfs;
        if (s <= 48) {
          const int ky = s / 7;
          const int kx = s - ky * 7;
          // ---- A frags (weights) + pair-swapped copies
          const char* wb = slotBase + (halfs << 12) + laneA;
          short8 aW[4], aS[4];
#pragma unroll
          for (int j = 0; j < 4; ++j) {
            aW[j] = *(const short8*)(wb + j * 1024);
            uint4v u = __builtin_bit_cast(uint4v, aW[j]);
            u.x = rot16(u.x); u.y = rot16(u.y);
            u.z = rot16(u.z); u.w = rot16(u.w);
            aS[j] = __builtin_bit_cast(short8, u);
          }
          // ---- B frags (X pixels) + MFMA
          const int klx = kx + lm;
          const int key = ((klx >> 1) & 3) << 4;
          const char* bbase =
              smem + ((wv + ky) * 70 + klx) * 64 + ((lg << 4) ^ key);
#pragma unroll
          for (int f = 0; f < 4; ++f) {
            short8 bf = *(const short8*)(bbase + f * 1024);
#pragma unroll
            for (int j = 0; j < 4; ++j) {
              acc[j][f] = __builtin_amdgcn_mfma_f32_16x16x32_bf16(
                  aW[j], bf, acc[j][f], 0, 0, 0);
              acc[j][f] = __builtin_amdgcn_mfma_f32_16x16x32_bf16(
                  aS[j], bf, acc[j][f], 0, 0, 0);
            }
          }
        }
      }
      // ---- W pipeline: write pair p+1 into other slot; prefetch pair p+2
      if (p < 24) {
        *(short8*)(smem + LDSW + (((p + 1) & 1) << 13) + wdstOff) = wreg;
        if (p < 23) {
          int snext = 2 * (p + 2) + sub;
          if (snext > 48) snext = 48;  // clamp (pair 24 tail)
          wreg = *(const short8*)(wsrcBase + (size_t)snext * 57344);
        }
      }
      __syncthreads();  // one barrier per PAIR of slices
    }
  }

  // ---- epilogue (r7-verified logic, 8-row geometry) ----
  float bia[4][4];
#pragma unroll
  for (int j = 0; j < 4; ++j)
#pragma unroll
    for (int r = 0; r < 4; ++r) bia[j][r] = biasPad[oc0 + j * 16 + lg * 4 + r];

  // theta full-res dual-bf16 (no smem involved)
#pragma unroll
  for (int j = 0; j < 4; ++j) {
#pragma unroll
    for (int f = 0; f < 4; ++f) {
#pragma unroll
      for (int r = 0; r < 4; ++r) {
        int ch = oc0 + j * 16 + lg * 4 + r;
        if (ch < 100) {
          int n = py * 64 + f * 16 + lm;
          float v = acc[j][f][r] + bia[j][r];
          unsigned short hi = f2bf_rne(v);
          float hif = __builtin_bit_cast(float, ((unsigned int)hi) << 16);
          unsigned short lo = f2bf_rne(v - hif);
          thd_dw[(((size_t)(b << 12) + n) << 7) + ch] =
              (unsigned int)hi | (((unsigned int)lo) << 16);
        }
      }
    }
  }

  __syncthreads();  // all waves done with smem compute reads
  float* scratch = (float*)smem;  // [4][64*33] floats (odd-row stash)

#pragma unroll
  for (int j = 0; j < 4; ++j) {
#pragma unroll
    for (int f = 0; f < 4; ++f) {
#pragma unroll
      for (int r = 0; r < 4; ++r) {
        float v = acc[j][f][r] + bia[j][r];
        float vn = fmaxf(v, __shfl_xor(v, 1));
        acc[j][f][r] = vn;  // keep for even waves
        if ((wv & 1) && !(lm & 1)) {
          int ch_local = j * 16 + lg * 4 + r;
          int mcol = f * 8 + (lm >> 1);
          scratch[(wv >> 1) * 2112 + ch_local * 33 + mcol] = vn;
        }
      }
    }
  }
  __syncthreads();

  if (!(wv & 1)) {
#pragma unroll
    for (int j = 0; j < 4; ++j) {
#pragma unroll
      for (int f = 0; f < 4; ++f) {
#pragma unroll
        for (int r = 0; r < 4; ++r) {
          if (!(lm & 1)) {
            int ch = oc0 + j * 16 + lg * 4 + r;
            int ch_local = j * 16 + lg * 4 + r;
            int mcol = f * 8 + (lm >> 1);
            float partner = scratch[(wv >> 1) * 2112 + ch_local * 33 + mcol];
            float vfinal = fmaxf(acc[j][f][r], partner);
            int m = (((oy0 >> 1) + (wv >> 1)) << 5) + mcol;
            if (ch >= 100 && ch < 200) {
              int c = ch - 100;
              unsigned short hi = f2bf_rne(vfinal);
              float hif = __builtin_bit_cast(float, ((unsigned int)hi) << 16);
              unsigned short lo = f2bf_rne(vfinal - hif);
              phd_dw[(((size_t)(b << 10) + m) << 7) + c] =
                  (unsigned int)hi | (((unsigned int)lo) << 16);
            } else if (ch >= 200 && ch < 400) {
              int cg = ch - 200;
              gP[((size_t)(b * 208 + cg) << 10) + m] = f2bf_rne(vfinal);
            }
          }
        }
      }
    }
  }
}

// ---------------------------------------------------------------------------
// attn_mfma: flash-style attention (unchanged from round 5, verified)
// ---------------------------------------------------------------------------
__global__ __launch_bounds__(512, 2) void attn_mfma_kernel(
    const unsigned short* __restrict__ thd,  // [8][4096][256]
    const unsigned short* __restrict__ phd,  // [8][1024][256]
    const unsigned short* __restrict__ gP,   // [8][208][1024]
    float* __restrict__ out) {               // [8][200][4096]
  __shared__ __align__(16) char sm[140800];
  float* corrL = (float*)(sm + 131072);   // [64][32]
  float* statsL = (float*)(sm + 139264);  // [64][2][2]
  float* mFinL = (float*)(sm + 140288);   // [64]
  float* invL = (float*)(sm + 140544);    // [64]

  const int bx = blockIdx.x;
  const int b = bx >> 6;
  const int n0 = (bx & 63) << 6;
  const int t = threadIdx.x;
  const int w = t >> 6;
  const int l = t & 63;
  const int lm = l & 15;
  const int lg = l >> 4;
  const int rowTile = w & 3;
  const int mhalf = w >> 2;
  const int rowB = rowTile * 16 + lg * 4;

  short8 aA[8], aS[8];
  {
    const unsigned short* ap =
        thd + (((size_t)(b << 12) + n0 + rowTile * 16 + lm) << 8) + lg * 8;
#pragma unroll
    for (int kf = 0; kf < 8; ++kf) {
      short8 v = *(const short8*)(ap + kf * 32);
      aA[kf] = v;
      uint4v u = __builtin_bit_cast(uint4v, v);
      u.x = rot16(u.x); u.y = rot16(u.y); u.z = rot16(u.z); u.w = rot16(u.w);
      aS[kf] = __builtin_bit_cast(short8, u);
    }
  }

  float mRun[4], sRun[4];
#pragma unroll
  for (int r = 0; r < 4; ++r) { mRun[r] = -3.0e38f; sRun[r] = 0.0f; }

  for (int step = 0; step < 16; ++step) {
    const int m0 = mhalf * 512 + step * 32;
    f32x4 ac0 = (f32x4)0.f, ac1 = (f32x4)0.f;
    const unsigned short* bp0 =
        phd + (((size_t)(b << 10) + m0 + lm) << 8) + lg * 8;
    const unsigned short* bp1 = bp0 + (16 << 8);
#pragma unroll
    for (int kf = 0; kf < 8; ++kf) {
      short8 bv0 = *(const short8*)(bp0 + kf * 32);
      short8 bv1 = *(const short8*)(bp1 + kf * 32);
      ac0 = __builtin_amdgcn_mfma_f32_16x16x32_bf16(aA[kf], bv0, ac0, 0, 0, 0);
      ac1 = __builtin_amdgcn_mfma_f32_16x16x32_bf16(aA[kf], bv1, ac1, 0, 0, 0);
      ac0 = __builtin_amdgcn_mfma_f32_16x16x32_bf16(aS[kf], bv0, ac0, 0, 0, 0);
      ac1 = __builtin_amdgcn_mfma_f32_16x16x32_bf16(aS[kf], bv1, ac1, 0, 0, 0);
    }
    float tmax[4], pv0[4], pv1[4], csum[4];
#pragma unroll
    for (int r = 0; r < 4; ++r) tmax[r] = fmaxf(ac0[r], ac1[r]);
#pragma unroll
    for (int s = 1; s < 16; s <<= 1)
#pragma unroll
      for (int r = 0; r < 4; ++r) tmax[r] = fmaxf(tmax[r], __shfl_xor(tmax[r], s));
#pragma unroll
    for (int r = 0; r < 4; ++r) {
      float mNew = fmaxf(mRun[r], tmax[r]);
      float scale = __expf(mRun[r] - mNew);
      pv0[r] = __expf(ac0[r] - mNew);
      pv1[r] = __expf(ac1[r] - mNew);
      csum[r] = pv0[r] + pv1[r];
      mRun[r] = mNew;
      sRun[r] *= scale;
    }
#pragma unroll
    for (int s = 1; s < 16; s <<= 1)
#pragma unroll
      for (int r = 0; r < 4; ++r) csum[r] += __shfl_xor(csum[r], s);
#pragma unroll
    for (int r = 0; r < 4; ++r) sRun[r] += csum[r];
#pragma unroll
    for (int r = 0; r < 4; ++r) {
      int row = rowB + r;
      int sw = ((row & 7) << 4);
      int byte0 = (row << 11) + ((((m0 + lm) << 1)) ^ sw);
      int byte1 = (row << 11) + ((((m0 + 16 + lm) << 1)) ^ sw);
      *(unsigned short*)(sm + byte0) = f2bf_rne(pv0[r]);
      *(unsigned short*)(sm + byte1) = f2bf_rne(pv1[r]);
    }
    if (lm == 0) {
      int chunkIdx = mhalf * 16 + step;
#pragma unroll
      for (int r = 0; r < 4; ++r) corrL[(rowB + r) * 32 + chunkIdx] = mRun[r];
    }
  }
  if (lm == 0) {
#pragma unroll
    for (int r = 0; r < 4; ++r) {
      statsL[((rowB + r) * 2 + mhalf) * 2 + 0] = mRun[r];
      statsL[((rowB + r) * 2 + mhalf) * 2 + 1] = sRun[r];
    }
  }
  __syncthreads();

  if (t < 64) {
    float m0v = statsL[(t * 2 + 0) * 2 + 0];
    float s0v = statsL[(t * 2 + 0) * 2 + 1];
    float m1v = statsL[(t * 2 + 1) * 2 + 0];
    float s1v = statsL[(t * 2 + 1) * 2 + 1];
    float mF = fmaxf(m0v, m1v);
    float sF = s0v * __expf(m0v - mF) + s1v * __expf(m1v - mF);
    mFinL[t] = mF;
    invL[t] = 1.0f / sF;
  }
  __syncthreads();

  {
    int idx = t * 4;
#pragma unroll
    for (int i = 0; i < 4; ++i) {
      int row = (idx + i) >> 5;
      corrL[idx + i] = __expf(corrL[idx + i] - mFinL[row]);
    }
  }
  __syncthreads();

  {
    int row = t >> 3;
    int mb = (t & 7) << 7;
    int sw = ((row & 7) << 4);
    for (int j = 0; j < 16; ++j) {
      int m = mb + j * 8;
      int byte = (row << 11) + (((m << 1)) ^ sw);
      float corr = corrL[row * 32 + (m >> 5)];
      short8 pv8 = *(short8*)(sm + byte);
      short8 ov;
#pragma unroll
      for (int e = 0; e < 8; ++e) {
        unsigned short us = (unsigned short)pv8[e];
        float f = __builtin_bit_cast(float, ((unsigned int)us) << 16);
        ov[e] = (short)f2bf_rne(f * corr);
      }
      *(short8*)(sm + byte) = ov;
    }
  }
  __syncthreads();

  const int nct = mhalf ? 6 : 7;
  const int ct0 = mhalf ? 7 : 0;
  f32x4 oacc[7];
#pragma unroll
  for (int i = 0; i < 7; ++i) oacc[i] = (f32x4)0.f;

  const int rowA = rowTile * 16 + lm;
  const int swA = ((rowA & 7) << 4);
  const int rowABase = (rowA << 11);

  for (int ks = 0; ks < 32; ++ks) {
    short8 ap = *(const short8*)(
        sm + rowABase + ((((ks * 32 + lg * 8) << 1)) ^ swA));
    const unsigned short* gbase =
        gP + ((size_t)(b * 208) << 10) + ks * 32 + lg * 8;
#pragma unroll
    for (int i = 0; i < 7; ++i) {
      if (i < nct) {
        int c = (ct0 + i) * 16 + lm;
        short8 gv = *(const short8*)(gbase + ((size_t)c << 10));
        oacc[i] = __builtin_amdgcn_mfma_f32_16x16x32_bf16(ap, gv, oacc[i], 0, 0, 0);
      }
    }
  }
  {
    float inv[4];
#pragma unroll
    for (int r = 0; r < 4; ++r) inv[r] = invL[rowB + r];
#pragma unroll
    for (int i = 0; i < 7; ++i) {
      if (i < nct) {
        int c = (ct0 + i) * 16 + lm;
        if (c < 200) {
          f32x4 v;
#pragma unroll
          for (int r = 0; r < 4; ++r) v[r] = oacc[i][r] * inv[r];
          *(f32x4*)(out + (((size_t)(b * 200 + c)) << 12) + n0 + rowB) = v;
        }
      }
    }
  }
}

// ---------------------------------------------------------------------------
extern "C" void kernel_launch(void* const* d_in, const int* in_sizes, int n_in,
                              void* d_out, int out_size, void* d_ws,
                              size_t ws_size, hipStream_t stream) {
  const float* x  = (const float*)d_in[0];
  const float* tw = (const float*)d_in[1];
  const float* tb = (const float*)d_in[2];
  const float* pw = (const float*)d_in[3];
  const float* pb = (const float*)d_in[4];
  const float* gw = (const float*)d_in[5];
  const float* gb = (const float*)d_in[6];
  float* out = (float*)d_out;

  unsigned short* ws_us = (unsigned short*)d_ws;
  unsigned short* thd = ws_us;               // 8*4096*256     = 8,388,608 us
  unsigned short* phd = ws_us + 8388608;     // 8*1024*256     = 2,097,152
  unsigned short* gP  = ws_us + 10485760;    // 8*208*1024     = 1,703,936
  unsigned short* xTi = ws_us + 12189696;    // 8*70*70*128    = 5,017,600
  unsigned short* wTi = ws_us + 17207296;    // 49*448*128     = 2,809,856
  float* biasPad = (float*)(ws_us + 20017152);  // 448 f (~40.1 MB total)

  prep_x<<<560, 256, 0, stream>>>(x, (unsigned int*)xTi);
  prep_w<<<5488, 256, 0, stream>>>(tw, pw, gw, (unsigned int*)wTi);
  prep_bias<<<2, 256, 0, stream>>>(tb, pb, gb, biasPad);
  zero_pads<<<4608, 256, 0, stream>>>((unsigned int*)thd, (unsigned int*)phd,
                                      (unsigned int*)gP);

  convmfma_kernel<<<dim3(64, 7), 512, 0, stream>>>(
      xTi, wTi, biasPad, (unsigned int*)thd, (unsigned int*)phd, gP);
  attn_mfma_kernel<<<512, 512, 0, stream>>>(thd, phd, gP, out);
}